// Round 13
// baseline (296.108 us; speedup 1.0000x reference)
//
#include <hip/hip_runtime.h>
#include <hip/hip_bf16.h>

#define NF 200
#define ND 32
#define NK 4
#define NH1 32
#define NH2 16
#define BN_EPS 1e-3f

// v + dpp_shuffled(v): all-VALU cross-lane add (no LDS pipe).
// CTRL: 0xB1 = quad_perm xor1, 0x4E = quad_perm xor2, 0x141 = row_half_mirror
// (xor 4 within 8), 0x128 = row_ror:8 (xor 8 within 16).
template<int CTRL>
__device__ __forceinline__ float dpp_add(float v) {
  const int r = __builtin_amdgcn_update_dpp(0, __float_as_int(v), CTRL, 0xF, 0xF, true);
  return v + __int_as_float(r);
}

typedef float vf4 __attribute__((ext_vector_type(4)));

// TWO rows per wave (independent load/compute streams interleave, smoothing
// the load/compute beat within each wave; tail+epilogue amortized over 2 rows).
// Per-row structure is EXACTLY R5's champion: 4-deep rotation, runtime
// guards, unrolling left to the compiler (forced variants all regressed:
// R6/R8/R11/R12). 8 KB LDS/block; (256,4) -> 128-VGPR budget, no spill.
__global__ __launch_bounds__(256, 4) void mvke_fused(
    const float* __restrict__ x, const float* __restrict__ tag,
    const float* __restrict__ vk,
    const float* __restrict__ W1, const float* __restrict__ b1,
    const float* __restrict__ g1, const float* __restrict__ be1,
    const float* __restrict__ m1, const float* __restrict__ v1,
    const float* __restrict__ W2, const float* __restrict__ b2,
    const float* __restrict__ g2, const float* __restrict__ be2,
    const float* __restrict__ m2, const float* __restrict__ v2,
    float* __restrict__ out, int nrows)
{
  __shared__ float ctx_s[8][NK*ND];   // per-row pooled context   (4 KB)
  __shared__ float h1_s[8][NK*NH1];   // per-row tower-1 output   (4 KB)

  const int tid  = threadIdx.x;
  const int wave = tid >> 6;
  const int lane = tid & 63;
  const int fg   = lane >> 3;
  const int dl   = lane & 7;
  const int rA   = blockIdx.x * 8 + wave * 2;
  const int rB   = rA + 1;
  const bool liveA = (rA < nrows);
  const bool liveB = (rB < nrows);

  // vkt[k][j] = vk[(4*dl+j), k]
  float vkt[NK][4];
  #pragma unroll
  for (int j = 0; j < 4; ++j) {
    const float4 vv = *(const float4*)(vk + (4*dl + j) * NK);
    vkt[0][j] = vv.x; vkt[1][j] = vv.y; vkt[2][j] = vv.z; vkt[3][j] = vv.w;
  }

  const float* xrowA = x + (size_t)(liveA ? rA : 0) * (NF*ND);
  const float* xrowB = x + (size_t)(liveB ? rB : 0) * (NF*ND);
  const int laneoff = fg*ND + dl*4;

  float cxA[NK], cyA[NK], czA[NK], cwA[NK], lsA[NK];
  float cxB[NK], cyB[NK], czB[NK], cwB[NK], lsB[NK];
  #pragma unroll
  for (int k = 0; k < NK; ++k) {
    cxA[k]=cyA[k]=czA[k]=cwA[k]=lsA[k]=0.f;
    cxB[k]=cyB[k]=czB[k]=cwB[k]=lsB[k]=0.f;
  }

  #define XLOADA(it) (*(const vf4*)(xrowA + (it)*(8*ND) + laneoff))
  #define XLOADB(it) (*(const vf4*)(xrowB + (it)*(8*ND) + laneoff))
  #define PROC(xa, cx, cy, cz, cw, ls)                                        \
    {                                                                         \
      _Pragma("unroll")                                                       \
      for (int k = 0; k < NK; ++k) {                                          \
        float t = xa[0]*vkt[k][0] + xa[1]*vkt[k][1]                           \
                + xa[2]*vkt[k][2] + xa[3]*vkt[k][3];                          \
        t = dpp_add<0xB1>(t);                                                 \
        t = dpp_add<0x4E>(t);                                                 \
        t = dpp_add<0x141>(t);                                                \
        const float p = __expf(t);     /* un-normalized softmax, fp32-safe */ \
        ls[k] += p;                                                           \
        cx[k] = fmaf(p, xa[0], cx[k]);                                        \
        cy[k] = fmaf(p, xa[1], cy[k]);                                        \
        cz[k] = fmaf(p, xa[2], cz[k]);                                        \
        cw[k] = fmaf(p, xa[3], cw[k]);                                        \
      }                                                                       \
    }
  #define PROCA(xa) PROC(xa, cxA, cyA, czA, cwA, lsA)
  #define PROCB(xa) PROC(xa, cxB, cyB, czB, cwB, lsB)

  // ---- stage 1: dual-row stream, R5's 4-deep rotation per row ----
  {
    vf4 a0 = XLOADA(0), b0 = XLOADB(0);
    vf4 a1 = XLOADA(1), b1v = XLOADB(1);
    vf4 a2 = XLOADA(2), b2v = XLOADB(2);
    vf4 a3 = XLOADA(3), b3v = XLOADB(3);
    for (int g = 0; g < 6; ++g) {
      const int base = g * 4;
      {
        const vf4 cA = a0, cB = b0;
        if (base + 4 < NF/8) { a0 = XLOADA(base + 4); b0 = XLOADB(base + 4); }
        PROCA(cA); PROCB(cB);
      }
      {
        const vf4 cA = a1, cB = b1v;
        if (base + 5 < NF/8) { a1 = XLOADA(base + 5); b1v = XLOADB(base + 5); }
        PROCA(cA); PROCB(cB);
      }
      {
        const vf4 cA = a2, cB = b2v;
        if (base + 6 < NF/8) { a2 = XLOADA(base + 6); b2v = XLOADB(base + 6); }
        PROCA(cA); PROCB(cB);
      }
      {
        const vf4 cA = a3, cB = b3v;
        if (base + 7 < NF/8) { a3 = XLOADA(base + 7); b3v = XLOADB(base + 7); }
        PROCA(cA); PROCB(cB);
      }
    }
    PROCA(a0); PROCB(b0);   // tile 24
  }
  #undef PROCA
  #undef PROCB
  #undef PROC
  #undef XLOADA
  #undef XLOADB

  // ---- tail: combine the 8 f-groups for both rows ----
  const float scale = 0.17677669529663687f;  // 1/sqrt(32)
  #pragma unroll
  for (int k = 0; k < NK; ++k) {
    lsA[k] = dpp_add<0x128>(lsA[k]);
    cxA[k] = dpp_add<0x128>(cxA[k]);
    cyA[k] = dpp_add<0x128>(cyA[k]);
    czA[k] = dpp_add<0x128>(czA[k]);
    cwA[k] = dpp_add<0x128>(cwA[k]);
    lsB[k] = dpp_add<0x128>(lsB[k]);
    cxB[k] = dpp_add<0x128>(cxB[k]);
    cyB[k] = dpp_add<0x128>(cyB[k]);
    czB[k] = dpp_add<0x128>(czB[k]);
    cwB[k] = dpp_add<0x128>(cwB[k]);
    #pragma unroll
    for (int m = 16; m <= 32; m <<= 1) {
      lsA[k] += __shfl_xor(lsA[k], m);
      cxA[k] += __shfl_xor(cxA[k], m);
      cyA[k] += __shfl_xor(cyA[k], m);
      czA[k] += __shfl_xor(czA[k], m);
      cwA[k] += __shfl_xor(cwA[k], m);
      lsB[k] += __shfl_xor(lsB[k], m);
      cxB[k] += __shfl_xor(cxB[k], m);
      cyB[k] += __shfl_xor(cyB[k], m);
      czB[k] += __shfl_xor(czB[k], m);
      cwB[k] += __shfl_xor(cwB[k], m);
    }
  }

  if (fg == 0) {
    #pragma unroll
    for (int k = 0; k < NK; ++k) {
      const float invA = scale / lsA[k];
      float* pA = &ctx_s[wave*2][k*ND + dl*4];
      pA[0] = cxA[k]*invA; pA[1] = cyA[k]*invA;
      pA[2] = czA[k]*invA; pA[3] = cwA[k]*invA;
      const float invB = scale / lsB[k];
      float* pB = &ctx_s[wave*2+1][k*ND + dl*4];
      pB[0] = cxB[k]*invB; pB[1] = cyB[k]*invB;
      pB[2] = czB[k]*invB; pB[3] = cwB[k]*invB;
    }
  }
  __syncthreads();

  // ---- stage 2: tower 1 for both rows; weights from global/L2 ----
  #pragma unroll
  for (int rr = 0; rr < 2; ++rr) {
    #pragma unroll
    for (int rep = 0; rep < 2; ++rep) {
      const int o = lane + rep*64;
      const int k = o >> 5, h = o & 31;
      const float* wp = W1 + k*(ND*NH1) + h;
      const float* cp = &ctx_s[wave*2+rr][k*ND];
      float acc = 0.f;
      #pragma unroll
      for (int d = 0; d < ND; ++d) acc = fmaf(cp[d], wp[d*NH1], acc);
      const float a = g1[o] * rsqrtf(v1[o] + BN_EPS);
      const float c = fmaf(b1[o] - m1[o], a, be1[o]);
      h1_s[wave*2+rr][o] = fmaxf(fmaf(acc, a, c), 0.f);
    }
  }
  __syncthreads();

  // ---- stage 3: tower 2 + gate + output, per row ----
  #pragma unroll
  for (int rr = 0; rr < 2; ++rr) {
    const int row  = rA + rr;
    const bool live = (row < nrows);
    const int k3 = lane >> 4, j3 = lane & 15;
    const float* wp = W2 + k3*(NH1*NH2) + j3;
    const float* hp = &h1_s[wave*2+rr][k3*NH1];
    float acc = 0.f;
    #pragma unroll
    for (int h = 0; h < NH1; ++h) acc = fmaf(hp[h], wp[h*NH2], acc);
    const int o = k3*NH2 + j3;
    const float a2 = g2[o] * rsqrtf(v2[o] + BN_EPS);
    const float c2 = fmaf(b2[o] - m2[o], a2, be2[o]);
    const float h2v = fmaxf(fmaf(acc, a2, c2), 0.f);

    const float* tp = tag + (size_t)(live ? row : 0) * ND;
    float gs0=0.f, gs1=0.f, gs2=0.f, gs3=0.f;
    #pragma unroll
    for (int d = 0; d < ND; ++d) {
      const float t = tp[d];
      const float4 vv = *(const float4*)(vk + d*NK);
      gs0 = fmaf(t, vv.x, gs0);
      gs1 = fmaf(t, vv.y, gs1);
      gs2 = fmaf(t, vv.z, gs2);
      gs3 = fmaf(t, vv.w, gs3);
    }
    gs0 *= scale; gs1 *= scale; gs2 *= scale; gs3 *= scale;
    const float mx = fmaxf(fmaxf(gs0, gs1), fmaxf(gs2, gs3));
    const float e0 = __expf(gs0-mx), e1 = __expf(gs1-mx),
                e2 = __expf(gs2-mx), e3 = __expf(gs3-mx);
    const float esum = e0 + e1 + e2 + e3;
    const float ek = (k3 == 0) ? e0 : (k3 == 1) ? e1 : (k3 == 2) ? e2 : e3;

    float val = (ek / esum) * h2v;
    val += __shfl_xor(val, 16);
    val += __shfl_xor(val, 32);        // sum over the 4 experts
    if (live && lane < NH2) out[(size_t)row*NH2 + lane] = val;
  }
}

extern "C" void kernel_launch(void* const* d_in, const int* in_sizes, int n_in,
                              void* d_out, int out_size, void* d_ws, size_t ws_size,
                              hipStream_t stream) {
  const float* x   = (const float*)d_in[0];
  const float* tag = (const float*)d_in[1];
  const float* vk  = (const float*)d_in[2];
  const float* W1  = (const float*)d_in[3];
  const float* b1  = (const float*)d_in[4];
  const float* g1  = (const float*)d_in[5];
  const float* be1 = (const float*)d_in[6];
  const float* m1  = (const float*)d_in[7];
  const float* v1  = (const float*)d_in[8];
  const float* W2  = (const float*)d_in[9];
  const float* b2  = (const float*)d_in[10];
  const float* g2  = (const float*)d_in[11];
  const float* be2 = (const float*)d_in[12];
  const float* m2  = (const float*)d_in[13];
  const float* v2  = (const float*)d_in[14];
  float* out = (float*)d_out;

  const int nrows = in_sizes[1] / ND;          // B from tag_embedding
  const int nblocks = (nrows + 7) / 8;         // 4 waves/block, 2 rows/wave
  mvke_fused<<<nblocks, 256, 0, stream>>>(x, tag, vk, W1, b1, g1, be1, m1, v1,
                                          W2, b2, g2, be2, m2, v2, out, nrows);
}